// Round 6
// baseline (30493.527 us; speedup 1.0000x reference)
//
#include <hip/hip_runtime.h>
#include <hip/hip_bf16.h>
#include <stdint.h>

// ---------------------------------------------------------------------------
// DiffusionModel: 100 fused steps of x <- x + B*(x@Wx + t*csum + b) + s*noise
// R10: occupancy push. R9 matched prediction (5346us, VALUBusy 77.6%) but is
// pinned at 4 waves/SIMD (47% occ) by the (1024,4)=128-reg budget; serial
// threefry dep-chains + barrier-synced waves leave 22% issue-idle. This
// round: 512-thr blocks x 32 rows (grid 1024), SINGLE-buffered xs (33+4 KB
// -> 3 blocks/CU in LDS), __launch_bounds__(512,6) -> 85-reg budget,
// 6 waves/SIMD (75% occ target). Wave covers 64 cols: nt=0..3 sweeps,
// acc shrinks to 8 regs; xr 32 AGPR; est live ~78 <= 85.
// Kept from R9: RNG folded into K-sweep (8 chains/sweep at even c),
// rolling depth-2 W prefetch with t-invariant periodic addresses (now
// period = 4 sweeps x 16 chunks), packed bf16 stores.
// Cost accepted: 2 barriers/step (single buffer), W-requests back to 52 GB
// (R5 proved the memory system takes it; extra latency hidden by +50% waves).
//
// REGISTER MODEL (R2-R9 measured): budget = 512/launch_bounds_arg2.
// (1024,4)->128 ok for 110 live; (512,4)->64+64 with 32-elem state = 3.5 GB
// phantom scratch writes (R6). Spill alarm: WRITE_SIZE >> 0.45 GB.
// ---------------------------------------------------------------------------

typedef __attribute__((ext_vector_type(8))) short short8;
typedef __attribute__((ext_vector_type(4))) float f32x4;

#define XS_STRIDE 520          // bf16 elems per x-row in LDS (512+8 pad)
#define NSTEP 100

// Threefry-2x32, 20 rounds, exactly as jax._src.prng.threefry2x32
__device__ __forceinline__ void tf_rounds(uint32_t k0, uint32_t k1, uint32_t k2,
                                          uint32_t& a, uint32_t& b) {
  a += k0; b += k1;
#define TFR(r) { a += b; b = __builtin_rotateleft32(b, (r)); b ^= a; }
  TFR(13) TFR(15) TFR(26) TFR(6)   a += k1; b += k2 + 1u;
  TFR(17) TFR(29) TFR(16) TFR(24)  a += k2; b += k0 + 2u;
  TFR(13) TFR(15) TFR(26) TFR(6)   a += k0; b += k1 + 3u;
  TFR(17) TFR(29) TFR(16) TFR(24)  a += k1; b += k2 + 4u;
  TFR(13) TFR(15) TFR(26) TFR(6)   a += k2; b += k0 + 5u;
#undef TFR
}

// bits -> uniform[-0.99999994, 1) -> sqrt(2)*erfinv(u)  (XLA/Giles erfinv).
// Bit-identical to R5-R9 (RNG must match the JAX reference).
__device__ __forceinline__ float gauss_from_bits(uint32_t bits) {
  const float lo = __uint_as_float(0xBF7FFFFFu);   // nextafter(-1,0)
  float f = __uint_as_float((bits >> 9) | 0x3F800000u) - 1.0f;  // [0,1)
  float u = fmaxf(lo, fmaf(f, 2.0f, lo));
  float om = fmaf(u, -u, 1.0f);                    // 1-u^2 > 0
  float L = __log2f(om);                           // w = -ln2 * L
  float p;
  if (__builtin_expect(L > -7.2134752f, 1)) {      // w < 5
    float z = fmaf(-0.69314718f, L, -2.5f);        // w - 2.5
    p =            2.81022636e-08f;
    p = fmaf(p, z, 3.43273939e-07f);
    p = fmaf(p, z, -3.5233877e-06f);
    p = fmaf(p, z, -4.39150654e-06f);
    p = fmaf(p, z, 0.00021858087f);
    p = fmaf(p, z, -0.00125372503f);
    p = fmaf(p, z, -0.00417768164f);
    p = fmaf(p, z, 0.246640727f);
    p = fmaf(p, z, 1.50140941f);
  } else {
    float z = sqrtf(-0.69314718f * L) - 3.0f;
    p =            -0.000200214257f;
    p = fmaf(p, z, 0.000100950558f);
    p = fmaf(p, z, 0.00134934322f);
    p = fmaf(p, z, -0.00367342844f);
    p = fmaf(p, z, 0.00573950773f);
    p = fmaf(p, z, -0.0076224613f);
    p = fmaf(p, z, 0.00943887047f);
    p = fmaf(p, z, 1.00167406f);
    p = fmaf(p, z, 2.83297682f);
  }
  return 1.41421356f * (p * u);   // sqrt(2) * erfinv(u)
}

// f32 -> bf16 RNE (bit trick) — prep kernel only
__device__ __forceinline__ uint16_t f2bf(float f) {
  uint32_t u = __float_as_uint(f);
  u += 0x7FFFu + ((u >> 16) & 1u);
  return (uint16_t)(u >> 16);
}

// packed pair f32x2 -> bf16x2 (v_cvt_pk_bf16_f32; RNE == bit-trick on
// normal values, which is all x ever is here)
__device__ __forceinline__ uint32_t f2bf_pk(float lo, float hi) {
  union { __hip_bfloat162 h; uint32_t u; } cv;
  cv.h = __float22bfloat162_rn(make_float2(lo, hi));
  return cv.u;
}

// --------------------------------------------------------------------------
// Pre-pass 1: Wx (rows 0..511 of W) -> bf16 blob, UNPADDED [c][n][32]:
// chunk c holds k in [32c,32c+32); B-frag for (c,n,q) = 16B at n*64+q*16 B.
// --------------------------------------------------------------------------
__global__ void prep_w_kernel(const float* __restrict__ W, uint16_t* __restrict__ blob) {
  int id = blockIdx.x * 256 + threadIdx.x;
  if (id >= 512 * 512) return;
  int k = id >> 9;        // feature (K) index
  int n = id & 511;       // output col
  float v = W[k * 512 + n];
  int c = k >> 5, kk = k & 31;
  blob[c * 16384 + n * 32 + kk] = f2bf(v);
}

// Pre-pass 2: csum[n] = sum_j W[512+j][n]  (rank-1 t-embedding part)
__global__ void prep_csum_kernel(const float* __restrict__ W, float* __restrict__ csum) {
  int n = blockIdx.x * 256 + threadIdx.x;
  if (n >= 512) return;
  float s = 0.0f;
  for (int j = 0; j < 512; ++j) s += W[(512 + j) * 512 + n];
  csum[n] = s;
}

// --------------------------------------------------------------------------
// Main fused kernel. MFMA 16x16x32 bf16: A[m=lane&15][k=q*8+j] (from xs),
// B[k][n=lane&15] (direct global 16B coalesced load), C row=4q+reg.
// Block (512 thr) owns rows [32b, 32b+32): mt in {0,1}; wave w (0..7) covers
// cols [64w, 64w+64): nt in 0..3, four sequential K-sweeps with RNG
// interleaved (element e=c>>1 at even c). xs single-buffered, 2 barriers/step.
// W prefetch: rolling depth-2 over the periodic stream nt0c0..15,nt1,..,nt3,
// wrapping into the next step's nt0 (addresses t-invariant).
// --------------------------------------------------------------------------
__global__ __launch_bounds__(512, 6) void diffuse_kernel(
    const float* __restrict__ x0, const uint16_t* __restrict__ wblob,
    const float* __restrict__ csum, const float* __restrict__ bvec,
    float* __restrict__ out) {
  __shared__ alignas(16) uint16_t xs[32 * XS_STRIDE];   // 33280 B
  __shared__ alignas(8) float2 cb[512];                 // 4096 B {csum, bias}

  const int tid = threadIdx.x;     // 0..511
  const int l15 = tid & 15;
  const int q   = (tid >> 4) & 3;
  const int wv  = tid >> 6;        // wave 0..7
  const int blk = blockIdx.x;      // 0..1023

  cb[tid] = make_float2(csum[tid], bvec[tid]);

  int ncol[4];
#pragma unroll
  for (int nt = 0; nt < 4; ++nt)
    ncol[nt] = wv * 64 + nt * 16 + l15;

  // fp32 master of x, C-layout: (mt,nt)[j] = local row 16mt+4q+j, col ncol[nt]
  f32x4 xr[2][4];
#pragma unroll
  for (int mt = 0; mt < 2; ++mt)
#pragma unroll
    for (int j = 0; j < 4; ++j) {
      int gr = blk * 32 + mt * 16 + q * 4 + j;
#pragma unroll
      for (int nt = 0; nt < 4; ++nt)
        xr[mt][nt][j] = x0[gr * 512 + ncol[nt]];
    }

  // initial bf16 image (packed pairs: rows m, m+1)
#pragma unroll
  for (int mt = 0; mt < 2; ++mt)
#pragma unroll
    for (int nt = 0; nt < 4; ++nt)
#pragma unroll
      for (int jj = 0; jj < 2; ++jj) {
        int m = mt * 16 + q * 4 + jj * 2;
        uint32_t pk = f2bf_pk(xr[mt][nt][jj * 2], xr[mt][nt][jj * 2 + 1]);
        xs[m * XS_STRIDE + ncol[nt]] = (uint16_t)pk;
        xs[(m + 1) * XS_STRIDE + ncol[nt]] = (uint16_t)(pk >> 16);
      }

  const float sq2b = sqrtf(0.02f);   // sqrt(2*beta)
  const f32x4 vzero = {0.0f, 0.0f, 0.0f, 0.0f};

  // Single W base; stream position p (0..63) = nt*16+c maps to uint16 offset
  // (p&15)*16384 + (p>>4)*512. Depth-2 prefetch: bf0/bf1 = positions 0,1.
  const uint16_t* wb0 = wblob + ncol[0] * 32 + q * 8;
  short8 bf0 = *(const short8*)(wb0);
  short8 bf1 = *(const short8*)(wb0 + 16384);

  __syncthreads();   // init image + cb visible to all waves

  for (int t = 0; t < NSTEP; ++t) {
    // key_t = fold_in(key(42), t) = threefry((0,42),(0,t))
    uint32_t kt0 = 0u, kt1 = (uint32_t)t;
    tf_rounds(0u, 42u, 42u ^ 0x1BD11BDAu, kt0, kt1);
    const uint32_t kk2 = kt0 ^ kt1 ^ 0x1BD11BDAu;
    const float tf = (float)t;

#pragma unroll
    for (int nt = 0; nt < 4; ++nt) {
      f32x4 acc[2];
      acc[0] = vzero;
      acc[1] = vzero;

      const uint32_t base_e = (uint32_t)((blk * 32 + q * 4) * 512 + ncol[nt]);

      // ---- K sweep: consume bf0 (position nt*16+c), prefetch position +2
      //      (wraps across sweeps and into the next step); RNG chain for
      //      element e=c>>1 at even c fills the vmcnt stall slots ----
#pragma unroll
      for (int c = 0; c < 16; ++c) {
        const int pw = (nt * 16 + c + 2) & 63;
        short8 bf2 = *(const short8*)(wb0 + (pw & 15) * 16384 + (pw >> 4) * 512);
        {
          short8 af0 = *(const short8*)&xs[l15 * XS_STRIDE + c * 32 + q * 8];
          acc[0] = __builtin_amdgcn_mfma_f32_16x16x32_bf16(af0, bf0, acc[0], 0, 0, 0);
          short8 af1 = *(const short8*)&xs[(16 + l15) * XS_STRIDE + c * 32 + q * 8];
          acc[1] = __builtin_amdgcn_mfma_f32_16x16x32_bf16(af1, bf0, acc[1], 0, 0, 0);
        }
        if ((c & 1) == 0) {
          const int e = c >> 1, mt_e = e >> 2, j = e & 3;
          uint32_t a = 0u, b = base_e + (uint32_t)(mt_e * 8192 + j * 512);
          tf_rounds(kt0, kt1, kk2, a, b);
          float n = gauss_from_bits(a ^ b);
          xr[mt_e][nt][j] = fmaf(sq2b, n, xr[mt_e][nt][j]);   // x + s*noise
        }
        bf0 = bf1;
        bf1 = bf2;
      }

      // ---- score fold for this nt: x += B*(acc + t*csum + b) ----
      const float2 cbv = cb[ncol[nt]];
      const float tc = fmaf(tf, cbv.x, cbv.y);
#pragma unroll
      for (int mt = 0; mt < 2; ++mt)
#pragma unroll
        for (int j = 0; j < 4; ++j)
          xr[mt][nt][j] = fmaf(0.01f, acc[mt][j] + tc, xr[mt][nt][j]);
    }

    // ---- single-buffer xs rewrite: fence reads, write, fence writes ----
    if (t + 1 < NSTEP) {
      __syncthreads();   // all waves done reading xs for this step
#pragma unroll
      for (int mt = 0; mt < 2; ++mt)
#pragma unroll
        for (int nt = 0; nt < 4; ++nt)
#pragma unroll
          for (int jj = 0; jj < 2; ++jj) {
            int m = mt * 16 + q * 4 + jj * 2;
            uint32_t pk = f2bf_pk(xr[mt][nt][jj * 2], xr[mt][nt][jj * 2 + 1]);
            xs[m * XS_STRIDE + ncol[nt]] = (uint16_t)pk;
            xs[(m + 1) * XS_STRIDE + ncol[nt]] = (uint16_t)(pk >> 16);
          }
      __syncthreads();   // new image visible
    }
  }

  // final store (fp32)
#pragma unroll
  for (int mt = 0; mt < 2; ++mt)
#pragma unroll
    for (int j = 0; j < 4; ++j) {
      int gr = blk * 32 + mt * 16 + q * 4 + j;
#pragma unroll
      for (int nt = 0; nt < 4; ++nt)
        out[gr * 512 + ncol[nt]] = xr[mt][nt][j];
    }
}

extern "C" void kernel_launch(void* const* d_in, const int* in_sizes, int n_in,
                              void* d_out, int out_size, void* d_ws, size_t ws_size,
                              hipStream_t stream) {
  const float* x0 = (const float*)d_in[0];   // (32768, 512)
  const float* W  = (const float*)d_in[1];   // (1024, 512)
  const float* bv = (const float*)d_in[2];   // (512,)
  float* out = (float*)d_out;

  uint16_t* blob = (uint16_t*)d_ws;                     // 512 KB bf16 W-blob
  float* csum = (float*)((char*)d_ws + 16 * 16384 * 2); // +2 KB

  prep_w_kernel<<<dim3(1024), dim3(256), 0, stream>>>(W, blob);
  prep_csum_kernel<<<dim3(2), dim3(256), 0, stream>>>(W, csum);
  diffuse_kernel<<<dim3(1024), dim3(512), 0, stream>>>(x0, blob, csum, bv, out);
}

// Round 7
// 8022.867 us; speedup vs baseline: 3.8008x; 3.8008x over previous
//
#include <hip/hip_runtime.h>
#include <hip/hip_bf16.h>
#include <stdint.h>

// ---------------------------------------------------------------------------
// DiffusionModel: 100 fused steps of x <- x + B*(x@Wx + t*csum + b) + s*noise
// R11: occupancy push, attempt 2. R10's (512,6) failed because per-thread
// state stayed at 32 elems (~110 live) against an 85-reg budget -> 39 GB
// scratch. This round halves the STATE with the block: 1024-thr blocks own
// 32 rows (grid 1024) -> 16 elems/thread. Live: xr 16 + acc 8 (nt-split) +
// bf 12 + af 4 + addr ~8 + update-RNG ~8 => ~52-58 <= 64 budget of
// __launch_bounds__(1024,8) -> 2 blocks/CU, 8 waves/SIMD. The two blocks
// are INDEPENDENT barrier domains; update:sweep duty ~2.6:1, so one block's
// VALU-heavy update covers the other's W-latency-stalled sweep. RNG moves
// back to the update phase (R7-style) to keep sweep pressure minimal --
// TLP replaces R9's intra-thread interleave. xs double-buffered (2x33.3KB
// +4KB = 70.7KB; x2 blocks = 141KB <= 160KB) -> 1 barrier/step. Cost:
// W-requests back to 52 GB (R5 proved fine); covered by 2x wave count.
//
// REGISTER MODEL (R2-R10 measured): budget = 512/launch_bounds_arg2, VGPR+
// AGPR unified. Overcommit symptom: VGPR_Count reported ~half the budget +
// WRITE_SIZE in GBs of phantom scratch (R6: 3.56GB @128, R10: 39GB @85).
// Fit requires live-set <= ~0.9*budget. Spill alarm -> revert to R9.
// ---------------------------------------------------------------------------

typedef __attribute__((ext_vector_type(8))) short short8;
typedef __attribute__((ext_vector_type(4))) float f32x4;

#define XS_STRIDE 520          // bf16 elems per x-row in LDS (512+8 pad)
#define NSTEP 100

// Threefry-2x32, 20 rounds, exactly as jax._src.prng.threefry2x32
__device__ __forceinline__ void tf_rounds(uint32_t k0, uint32_t k1, uint32_t k2,
                                          uint32_t& a, uint32_t& b) {
  a += k0; b += k1;
#define TFR(r) { a += b; b = __builtin_rotateleft32(b, (r)); b ^= a; }
  TFR(13) TFR(15) TFR(26) TFR(6)   a += k1; b += k2 + 1u;
  TFR(17) TFR(29) TFR(16) TFR(24)  a += k2; b += k0 + 2u;
  TFR(13) TFR(15) TFR(26) TFR(6)   a += k0; b += k1 + 3u;
  TFR(17) TFR(29) TFR(16) TFR(24)  a += k1; b += k2 + 4u;
  TFR(13) TFR(15) TFR(26) TFR(6)   a += k2; b += k0 + 5u;
#undef TFR
}

// bits -> uniform[-0.99999994, 1) -> sqrt(2)*erfinv(u)  (XLA/Giles erfinv).
// Bit-identical to R5-R10 (RNG must match the JAX reference).
__device__ __forceinline__ float gauss_from_bits(uint32_t bits) {
  const float lo = __uint_as_float(0xBF7FFFFFu);   // nextafter(-1,0)
  float f = __uint_as_float((bits >> 9) | 0x3F800000u) - 1.0f;  // [0,1)
  float u = fmaxf(lo, fmaf(f, 2.0f, lo));
  float om = fmaf(u, -u, 1.0f);                    // 1-u^2 > 0
  float L = __log2f(om);                           // w = -ln2 * L
  float p;
  if (__builtin_expect(L > -7.2134752f, 1)) {      // w < 5
    float z = fmaf(-0.69314718f, L, -2.5f);        // w - 2.5
    p =            2.81022636e-08f;
    p = fmaf(p, z, 3.43273939e-07f);
    p = fmaf(p, z, -3.5233877e-06f);
    p = fmaf(p, z, -4.39150654e-06f);
    p = fmaf(p, z, 0.00021858087f);
    p = fmaf(p, z, -0.00125372503f);
    p = fmaf(p, z, -0.00417768164f);
    p = fmaf(p, z, 0.246640727f);
    p = fmaf(p, z, 1.50140941f);
  } else {
    float z = sqrtf(-0.69314718f * L) - 3.0f;
    p =            -0.000200214257f;
    p = fmaf(p, z, 0.000100950558f);
    p = fmaf(p, z, 0.00134934322f);
    p = fmaf(p, z, -0.00367342844f);
    p = fmaf(p, z, 0.00573950773f);
    p = fmaf(p, z, -0.0076224613f);
    p = fmaf(p, z, 0.00943887047f);
    p = fmaf(p, z, 1.00167406f);
    p = fmaf(p, z, 2.83297682f);
  }
  return 1.41421356f * (p * u);   // sqrt(2) * erfinv(u)
}

// f32 -> bf16 RNE (bit trick) — prep kernel only
__device__ __forceinline__ uint16_t f2bf(float f) {
  uint32_t u = __float_as_uint(f);
  u += 0x7FFFu + ((u >> 16) & 1u);
  return (uint16_t)(u >> 16);
}

// packed pair f32x2 -> bf16x2 (v_cvt_pk_bf16_f32; RNE == bit-trick on
// normal values, which is all x ever is here)
__device__ __forceinline__ uint32_t f2bf_pk(float lo, float hi) {
  union { __hip_bfloat162 h; uint32_t u; } cv;
  cv.h = __float22bfloat162_rn(make_float2(lo, hi));
  return cv.u;
}

// --------------------------------------------------------------------------
// Pre-pass 1: Wx (rows 0..511 of W) -> bf16 blob, UNPADDED [c][n][32]:
// chunk c holds k in [32c,32c+32); B-frag for (c,n,q) = 16B at n*64+q*16 B.
// --------------------------------------------------------------------------
__global__ void prep_w_kernel(const float* __restrict__ W, uint16_t* __restrict__ blob) {
  int id = blockIdx.x * 256 + threadIdx.x;
  if (id >= 512 * 512) return;
  int k = id >> 9;        // feature (K) index
  int n = id & 511;       // output col
  float v = W[k * 512 + n];
  int c = k >> 5, kk = k & 31;
  blob[c * 16384 + n * 32 + kk] = f2bf(v);
}

// Pre-pass 2: csum[n] = sum_j W[512+j][n]  (rank-1 t-embedding part)
__global__ void prep_csum_kernel(const float* __restrict__ W, float* __restrict__ csum) {
  int n = blockIdx.x * 256 + threadIdx.x;
  if (n >= 512) return;
  float s = 0.0f;
  for (int j = 0; j < 512; ++j) s += W[(512 + j) * 512 + n];
  csum[n] = s;
}

// --------------------------------------------------------------------------
// Main fused kernel. MFMA 16x16x32 bf16: A[m=lane&15][k=q*8+j] (from xs),
// B[k][n=lane&15] (direct global 16B coalesced load), C row=4q+reg.
// Block (1024 thr, 16 waves) owns rows [32b, 32b+32): mt in {0,1}; wave w
// covers cols [32w,32w+32): nt in {0,1}, two sequential K-sweeps. RNG in
// the update phase (min sweep pressure). xs double-buffered, 1 barrier/step.
// W prefetch: rolling depth-2 over the periodic 32-position stream
// (nt0 c0..15, nt1 c0..15), wrapping into the next step (t-invariant addrs).
// --------------------------------------------------------------------------
__global__ __launch_bounds__(1024, 8) void diffuse_kernel(
    const float* __restrict__ x0, const uint16_t* __restrict__ wblob,
    const float* __restrict__ csum, const float* __restrict__ bvec,
    float* __restrict__ out) {
  __shared__ alignas(16) uint16_t xs[2][32 * XS_STRIDE];  // 2 x 33280 B
  __shared__ alignas(8) float2 cb[512];                   // 4096 B {csum, bias}

  const int tid = threadIdx.x;     // 0..1023
  const int l15 = tid & 15;
  const int q   = (tid >> 4) & 3;
  const int wv  = tid >> 6;        // wave 0..15
  const int blk = blockIdx.x;      // 0..1023

  if (tid < 512) cb[tid] = make_float2(csum[tid], bvec[tid]);

  int ncol[2];
#pragma unroll
  for (int nt = 0; nt < 2; ++nt)
    ncol[nt] = wv * 32 + nt * 16 + l15;

  // fp32 master of x, C-layout: (mt,nt)[j] = local row 16mt+4q+j, col ncol[nt]
  f32x4 xr[2][2];
#pragma unroll
  for (int mt = 0; mt < 2; ++mt)
#pragma unroll
    for (int j = 0; j < 4; ++j) {
      int gr = blk * 32 + mt * 16 + q * 4 + j;
#pragma unroll
      for (int nt = 0; nt < 2; ++nt)
        xr[mt][nt][j] = x0[gr * 512 + ncol[nt]];
    }

  // initial bf16 image into buffer 0 (packed pairs: rows m, m+1)
#pragma unroll
  for (int mt = 0; mt < 2; ++mt)
#pragma unroll
    for (int nt = 0; nt < 2; ++nt)
#pragma unroll
      for (int jj = 0; jj < 2; ++jj) {
        int m = mt * 16 + q * 4 + jj * 2;
        uint32_t pk = f2bf_pk(xr[mt][nt][jj * 2], xr[mt][nt][jj * 2 + 1]);
        xs[0][m * XS_STRIDE + ncol[nt]] = (uint16_t)pk;
        xs[0][(m + 1) * XS_STRIDE + ncol[nt]] = (uint16_t)(pk >> 16);
      }

  const float sq2b = sqrtf(0.02f);   // sqrt(2*beta)
  const f32x4 vzero = {0.0f, 0.0f, 0.0f, 0.0f};

  // W stream: position p = nt*16 + c in [0,32); uint16 offset of the 16B
  // fragment = (p&15)*16384 + (p>>4)*512 + voff, voff = wv*1024+l15*32+q*8.
  // Depth-2 rolling prefetch; addresses t-invariant (wraps across steps).
  const uint16_t* wbase = wblob + (wv * 1024 + l15 * 32 + q * 8);
  short8 bf0 = *(const short8*)(wbase);
  short8 bf1 = *(const short8*)(wbase + 16384);

  __syncthreads();   // init image + cb visible to all waves

  for (int t = 0; t < NSTEP; ++t) {
    const uint16_t* xsc = xs[t & 1];
    uint16_t* xsn = xs[(t + 1) & 1];

    // key_t = fold_in(key(42), t) = threefry((0,42),(0,t))  [uniform -> SALU]
    uint32_t kt0 = 0u, kt1 = (uint32_t)t;
    tf_rounds(0u, 42u, 42u ^ 0x1BD11BDAu, kt0, kt1);
    const uint32_t kk2 = kt0 ^ kt1 ^ 0x1BD11BDAu;
    const float tf = (float)t;

#pragma unroll
    for (int nt = 0; nt < 2; ++nt) {
      f32x4 acc[2];
      acc[0] = vzero;
      acc[1] = vzero;

      // ---- K sweep (lean: no RNG, 2 ds_read_b128 + 2 MFMA per W-load) ----
#pragma unroll
      for (int c = 0; c < 16; ++c) {
        const int p2 = (nt * 16 + c + 2) & 31;
        short8 bf2 = *(const short8*)(wbase + (p2 & 15) * 16384 + (p2 >> 4) * 512);
        short8 af0 = *(const short8*)&xsc[l15 * XS_STRIDE + c * 32 + q * 8];
        acc[0] = __builtin_amdgcn_mfma_f32_16x16x32_bf16(af0, bf0, acc[0], 0, 0, 0);
        short8 af1 = *(const short8*)&xsc[(16 + l15) * XS_STRIDE + c * 32 + q * 8];
        acc[1] = __builtin_amdgcn_mfma_f32_16x16x32_bf16(af1, bf0, acc[1], 0, 0, 0);
        bf0 = bf1;
        bf1 = bf2;
      }

      // ---- noise + update for this half (VALU only, barrier-free) ----
      const float2 cbv = cb[ncol[nt]];
      const float tc = fmaf(tf, cbv.x, cbv.y);
      const uint32_t base_e = (uint32_t)((blk * 32 + q * 4) * 512 + ncol[nt]);
#pragma unroll
      for (int mt = 0; mt < 2; ++mt) {
#pragma unroll
        for (int j = 0; j < 4; ++j) {
          float sc = acc[mt][j] + tc;
          float xv = fmaf(0.01f, sc, xr[mt][nt][j]);  // x + B*score (ref order)
          uint32_t a = 0u, b = base_e + (uint32_t)(mt * 8192 + j * 512);
          tf_rounds(kt0, kt1, kk2, a, b);
          float n = gauss_from_bits(a ^ b);
          xr[mt][nt][j] = fmaf(sq2b, n, xv);          // + s*noise
        }
        // next-step image (other buffer; fenced by end-of-step barriers)
        if (t + 1 < NSTEP) {
#pragma unroll
          for (int jj = 0; jj < 2; ++jj) {
            int m = mt * 16 + q * 4 + jj * 2;
            uint32_t pk = f2bf_pk(xr[mt][nt][jj * 2], xr[mt][nt][jj * 2 + 1]);
            xsn[m * XS_STRIDE + ncol[nt]] = (uint16_t)pk;
            xsn[(m + 1) * XS_STRIDE + ncol[nt]] = (uint16_t)(pk >> 16);
          }
        }
      }
    }

    if (t + 1 < NSTEP) __syncthreads();
  }

  // final store (fp32)
#pragma unroll
  for (int mt = 0; mt < 2; ++mt)
#pragma unroll
    for (int j = 0; j < 4; ++j) {
      int gr = blk * 32 + mt * 16 + q * 4 + j;
#pragma unroll
      for (int nt = 0; nt < 2; ++nt)
        out[gr * 512 + ncol[nt]] = xr[mt][nt][j];
    }
}

extern "C" void kernel_launch(void* const* d_in, const int* in_sizes, int n_in,
                              void* d_out, int out_size, void* d_ws, size_t ws_size,
                              hipStream_t stream) {
  const float* x0 = (const float*)d_in[0];   // (32768, 512)
  const float* W  = (const float*)d_in[1];   // (1024, 512)
  const float* bv = (const float*)d_in[2];   // (512,)
  float* out = (float*)d_out;

  uint16_t* blob = (uint16_t*)d_ws;                     // 512 KB bf16 W-blob
  float* csum = (float*)((char*)d_ws + 16 * 16384 * 2); // +2 KB

  prep_w_kernel<<<dim3(1024), dim3(256), 0, stream>>>(W, blob);
  prep_csum_kernel<<<dim3(2), dim3(256), 0, stream>>>(W, csum);
  diffuse_kernel<<<dim3(1024), dim3(1024), 0, stream>>>(x0, blob, csum, bv, out);
}